// Round 11
// baseline (221.056 us; speedup 1.0000x reference)
//
#include <hip/hip_runtime.h>
#include <math.h>

typedef unsigned short u16;
typedef short v8s __attribute__((ext_vector_type(8)));
typedef float v4f __attribute__((ext_vector_type(4)));

#define AS1 __attribute__((address_space(1)))
#define AS3 __attribute__((address_space(3)))

__device__ __forceinline__ float bf2f(u16 u) {
    union { unsigned int i; float f; } c; c.i = ((unsigned int)u) << 16; return c.f;
}
__device__ __forceinline__ u16 f2bf(float f) {
    union { float f; unsigned int i; } c; c.f = f;
    unsigned int u = c.i;
    return (u16)((u + 0x7FFFu + ((u >> 16) & 1u)) >> 16);
}
// async global->LDS, 16B per lane. LDS dest = base + lane*16 (wave-uniform base).
__device__ __forceinline__ void gload_lds16(const void* g, void* l) {
    __builtin_amdgcn_global_load_lds((const AS1 void*)(uintptr_t)g,
                                     (AS3 void*)(unsigned int)(uintptr_t)l,
                                     16, 0, 0);
}

#define Nn 32
#define Tt 64
#define Vv 25
#define NP 51200        // N*T*V positions
#define NBLK 400        // M-tiles (51200/128); psum layout [256 d][400 m]

// ---------------------------------------------------------------------------
// prep: frag-major packed bf16 weights + bias2[w][d] + zero pad.
// Pack layout (per GEMM): Bp[kt][wn(4)][nf(4)][kk(2)][lane(64)][e(8)] u16,
// so a wave's B-fragment load is 64 lanes x 16B CONTIGUOUS (1KB burst).
// Element: d = wn*64+nf*16+(lane&15); k = kt*64+kk*32+(lane>>4)*8+e.
// TCN:  val = Wt[(d*256+c)*9+dt], dt=k/256, c=k%256  (k over 2304)
// GCN:  val = Wg[(k3*256+d)*256+c], k3=k/256, c=k%256 (k over 768)
// ---------------------------------------------------------------------------
__global__ __launch_bounds__(256) void prep_kernel(
    const float* __restrict__ Wg, const float* __restrict__ Wt,
    const float* __restrict__ A, const float* __restrict__ bg,
    u16* __restrict__ Bpg, u16* __restrict__ Bpt,
    float* __restrict__ bias2, float* __restrict__ zpad)
{
    const int idx = blockIdx.x * 256 + threadIdx.x;
    const int stride = gridDim.x * 256;
    // TCN pack: 256*2304 = 589824 u16
    for (int i = idx; i < 589824; i += stride) {
        const int e = i & 7, lane = (i >> 3) & 63, rest = i >> 9;
        const int kk = rest & 1, nf = (rest >> 1) & 3, wn = (rest >> 3) & 3, kt = rest >> 5;
        const int d = wn * 64 + nf * 16 + (lane & 15);
        const int k = kt * 64 + kk * 32 + (lane >> 4) * 8 + e;
        const int dt = k >> 8, c = k & 255;
        Bpt[i] = f2bf(Wt[(d * 256 + c) * 9 + dt]);
    }
    // GCN pack: 256*768 = 196608 u16
    for (int i = idx; i < 196608; i += stride) {
        const int e = i & 7, lane = (i >> 3) & 63, rest = i >> 9;
        const int kk = rest & 1, nf = (rest >> 1) & 3, wn = (rest >> 3) & 3, kt = rest >> 5;
        const int d = wn * 64 + nf * 16 + (lane & 15);
        const int k = kt * 64 + kk * 32 + (lane >> 4) * 8 + e;
        const int k3 = k >> 8, c = k & 255;
        Bpg[i] = f2bf(Wg[(k3 * 256 + d) * 256 + c]);
    }
    for (int i = idx; i < 25 * 256; i += stride) {
        int w = i >> 8, d = i & 255;
        float s = 0.f;
        for (int k = 0; k < 3; ++k) {
            float cs = 0.f;
            for (int v = 0; v < 25; ++v) cs += A[(k * 25 + v) * 25 + w];
            s += bg[k * 256 + d] * cs;
        }
        bias2[i] = s;
    }
    for (int i = idx; i < 256; i += stride) zpad[i] = 0.f;
}

// ---------------------------------------------------------------------------
// xa2[p=(n,t,w)][k*256+c] = sum_v x[n,c,t,v] * A[k,v,w]   (bf16 out)
// Thread = c; x-row in registers; A reads wave-uniform (s_load).
// ---------------------------------------------------------------------------
__global__ __launch_bounds__(256) void xa_kernel(
    const float* __restrict__ x, const float* __restrict__ A,
    u16* __restrict__ xa2)
{
    const int t = blockIdx.x, n = blockIdx.y;
    const int tid = threadIdx.x;              // = c
    __shared__ float xs[256 * 25];            // 25.6 KB

    for (int i = tid; i < 6400; i += 256) {
        int c = i / 25, v = i - c * 25;
        xs[i] = x[((n * 256 + c) * 64 + t) * 25 + v];
    }
    __syncthreads();

    float xr[25];
    #pragma unroll
    for (int v = 0; v < 25; ++v) xr[v] = xs[tid * 25 + v];

    const size_t pbase = ((size_t)n * 64 + t) * 25;
    #pragma unroll 1
    for (int k = 0; k < 3; ++k) {
        float o[25];
        #pragma unroll
        for (int w = 0; w < 25; ++w) {
            float acc = 0.f;
            #pragma unroll
            for (int v = 0; v < 25; ++v)
                acc = fmaf(xr[v], A[(k * 25 + v) * 25 + w], acc);
            o[w] = acc;
        }
        u16* dst = xa2 + k * 256 + tid;
        #pragma unroll
        for (int w = 0; w < 25; ++w)
            dst[(pbase + w) * 768] = f2bf(o[w]);
    }
}

// ---------------------------------------------------------------------------
// GEMM, 128x256 tile (BN = full N), BK=64, 512 threads = 8 waves (2M x 4N,
// per-wave 64x64 = 4x4 frags). r3's proven 2-barrier loop. KEY CHANGE:
// B never touches LDS -- each wave loads its B-fragments global->register
// from the frag-major pack (coalesced 1KB bursts, L2-resident 1.2MB).
// LDS = A-tile only (16 KB): per-K-tile LDS traffic 176KB -> 80KB (2.2x),
// attacking the measured LDS-BW bound (MfmaUtil cap ~43% -> ~69%).
// Grid: 400 m-tiles, bijective XCD swizzle (chunks of 50 per XCD).
// A XOR-swizzle: inverse-swizzled GLOBAL source + swizzled ds_read (rule 21).
// TCN=true: A rows are t-shifted y2T reads (zero-pad at t edges); epilogue
// emits bf16 z + deterministic per-(d, m-tile) BN partials.
// ---------------------------------------------------------------------------
template<int KTOT, bool TCN>
__global__ __launch_bounds__(512) void gemm_kernel(
    const u16* __restrict__ Ad, const u16* __restrict__ Bp,
    const float* __restrict__ bias, u16* __restrict__ outB,
    float* __restrict__ psum, float* __restrict__ psq,
    const u16* __restrict__ zpad)
{
    constexpr int NT = KTOT / 64;
    __shared__ u16 smem[8192];           // 16 KB: A-tile only

    const int tid = threadIdx.x;
    const int wid = tid >> 6, lane = tid & 63;
    const int lr = lane & 15, hk = lane >> 4;
    const int wm = wid >> 2, wn = wid & 3;   // 2M x 4N wave grid
    const int rA = lane >> 3, sA = lane & 7;

    // bijective XCD swizzle for grid 400 (400 % 8 == 0): chunk of 50 per XCD
    const int orig = blockIdx.x;
    const int m = (orig & 7) * 50 + (orig >> 3);

    u16* As = smem;                      // [128 rows][64 k] swizzled

    v4f acc[4][4];
    const v4f vzero = {0.f, 0.f, 0.f, 0.f};
    #pragma unroll
    for (int mf = 0; mf < 4; ++mf)
        #pragma unroll
        for (int nf = 0; nf < 4; ++nf) acc[mf][nf] = vzero;

    for (int kt = 0; kt < NT; ++kt) {
        // ---- B-fragments: global->reg, frag-major pack, coalesced, L2-hot ----
        v8s b[4][2];
        {
            const u16* bw = Bp + (((size_t)kt * 4 + wn) << 12) + lane * 8;
            #pragma unroll
            for (int nf = 0; nf < 4; ++nf)
                #pragma unroll
                for (int kk = 0; kk < 2; ++kk)
                    b[nf][kk] = *(const v8s*)(bw + ((nf * 2 + kk) << 9));
        }
        // ---- stage A: 16 chunks (chunk = 8 rows x 128B); wave does 2 ----
        #pragma unroll
        for (int i = 0; i < 2; ++i) {
            const int ch = wid + i * 8;
            const int row = ch * 8 + rA;
            const int ss = sA ^ rA;              // row&7 == rA
            const u16* srcA;
            if (TCN) {
                const int dt = kt >> 2, c0 = (kt & 3) << 6;
                const int p = m * 128 + row;
                const int t = (p % 1600) / 25;
                const int tp = t + dt - 4;
                srcA = ((unsigned)tp < 64u)
                     ? (Ad + (size_t)(p + (dt - 4) * 25) * 256 + c0 + ss * 8)
                     : zpad;
            } else {
                srcA = Ad + (size_t)(m * 128 + row) * 768 + kt * 64 + ss * 8;
            }
            gload_lds16(srcA, (char*)As + ch * 1024);
        }
        __syncthreads();   // drains vmcnt(0): staged A (and b-frags) ready

        v8s a[4][2];
        #pragma unroll
        for (int mf = 0; mf < 4; ++mf)
            #pragma unroll
            for (int kk = 0; kk < 2; ++kk) {
                const int row = wm * 64 + mf * 16 + lr;
                const int slot = kk * 4 + hk;
                a[mf][kk] = *(const v8s*)((const char*)As + row * 128 + ((slot ^ (row & 7)) << 4));
            }
        #pragma unroll
        for (int kk = 0; kk < 2; ++kk)
            #pragma unroll
            for (int mf = 0; mf < 4; ++mf)
                #pragma unroll
                for (int nf = 0; nf < 4; ++nf)
                    acc[mf][nf] = __builtin_amdgcn_mfma_f32_16x16x32_bf16(
                        a[mf][kk], b[nf][kk], acc[mf][nf], 0, 0, 0);
        __syncthreads();   // protect LDS from next stage
    }

    // ---- epilogue ----
    if (!TCN) {
        #pragma unroll
        for (int mf = 0; mf < 4; ++mf) {
            #pragma unroll
            for (int j = 0; j < 4; ++j) {
                const int p = m * 128 + wm * 64 + mf * 16 + hk * 4 + j;
                const int w = p % 25;
                #pragma unroll
                for (int nf = 0; nf < 4; ++nf) {
                    const int d = wn * 64 + nf * 16 + lr;
                    outB[(size_t)p * 256 + d] = f2bf(acc[mf][nf][j] + bias[w * 256 + d]);
                }
            }
        }
    } else {
        float s[4], q[4];
        #pragma unroll
        for (int nf = 0; nf < 4; ++nf) {
            const int d = wn * 64 + nf * 16 + lr;
            const float bb = bias[d];
            s[nf] = 0.f; q[nf] = 0.f;
            #pragma unroll
            for (int mf = 0; mf < 4; ++mf) {
                #pragma unroll
                for (int j = 0; j < 4; ++j) {
                    const int p = m * 128 + wm * 64 + mf * 16 + hk * 4 + j;
                    const float zz = acc[mf][nf][j] + bb;
                    outB[(size_t)p * 256 + d] = f2bf(zz);
                    s[nf] += zz; q[nf] += zz * zz;
                }
            }
            s[nf] += __shfl_xor(s[nf], 16); s[nf] += __shfl_xor(s[nf], 32);
            q[nf] += __shfl_xor(q[nf], 16); q[nf] += __shfl_xor(q[nf], 32);
        }
        __syncthreads();
        float* red = (float*)smem;       // [2 wm][256 d] s, then q (4KB)
        if (hk == 0) {
            #pragma unroll
            for (int nf = 0; nf < 4; ++nf) {
                const int d = wn * 64 + nf * 16 + lr;
                red[wm * 256 + d] = s[nf];
                red[512 + wm * 256 + d] = q[nf];
            }
        }
        __syncthreads();
        if (tid < 256) {
            psum[(size_t)tid * NBLK + m] = red[tid] + red[256 + tid];
            psq[(size_t)tid * NBLK + m]  = red[512 + tid] + red[768 + tid];
        }
    }
}

// ---------------------------------------------------------------------------
// BN stats: reduce 400 m-tile partials per channel -> scale/shift
// ---------------------------------------------------------------------------
__global__ __launch_bounds__(256) void bn_stats_kernel(
    const float* __restrict__ psum, const float* __restrict__ psq,
    const float* __restrict__ gamma, const float* __restrict__ beta,
    float* __restrict__ scale, float* __restrict__ shift)
{
    const int d = blockIdx.x, tid = threadIdx.x;
    float s = 0.f, q = 0.f;
    for (int i = tid; i < NBLK; i += 256) {
        s += psum[(size_t)d * NBLK + i];
        q += psq[(size_t)d * NBLK + i];
    }
    #pragma unroll
    for (int off = 32; off; off >>= 1) {
        s += __shfl_down(s, off);
        q += __shfl_down(q, off);
    }
    __shared__ float rs[4], rq[4];
    if ((tid & 63) == 0) { rs[tid >> 6] = s; rq[tid >> 6] = q; }
    __syncthreads();
    if (tid == 0) {
        s = rs[0] + rs[1] + rs[2] + rs[3];
        q = rq[0] + rq[1] + rq[2] + rq[3];
        const float mean = s / 51200.f;
        const float var = q / 51200.f - mean * mean;
        const float inv = rsqrtf(var + 1e-5f);
        scale[d] = gamma[d] * inv;
        shift[d] = beta[d] - gamma[d] * inv * mean;
    }
}

// ---------------------------------------------------------------------------
// out[n,d,tv] = relu(z[p][d]*scale[d]+shift[d] + x[n,d,tv]); LDS transpose.
// ---------------------------------------------------------------------------
__global__ __launch_bounds__(256) void bn_apply_kernel(
    const u16* __restrict__ zb, const float* __restrict__ x,
    const float* __restrict__ scale, const float* __restrict__ shift,
    float* __restrict__ out)
{
    const int chunk = blockIdx.x;   // 0..24
    const int n = blockIdx.y;       // 0..31
    const int tid = threadIdx.x;
    __shared__ u16 zs[128 * 66];    // 16.9 KB, padded rows
    const size_t p0 = (size_t)n * 1600 + chunk * 64;

    for (int half = 0; half < 2; ++half) {
        const int d0 = half * 128;
        if (half) __syncthreads();
        for (int i = tid; i < 128 * 64; i += 256) {
            const int pl = i >> 7, dl = i & 127;
            zs[dl * 66 + pl] = zb[(p0 + pl) * 256 + d0 + dl];
        }
        __syncthreads();
        for (int i = tid; i < 128 * 64; i += 256) {
            const int dl = i >> 6, j = i & 63;
            const int d = d0 + dl;
            const size_t addr = ((size_t)n * 256 + d) * 1600 + chunk * 64 + j;
            const float r = bf2f(zs[dl * 66 + j]) * scale[d] + shift[d] + x[addr];
            out[addr] = fmaxf(r, 0.f);
        }
    }
}

extern "C" void kernel_launch(void* const* d_in, const int* in_sizes, int n_in,
                              void* d_out, int out_size, void* d_ws, size_t ws_size,
                              hipStream_t stream)
{
    const float* x     = (const float*)d_in[0];
    const float* A     = (const float*)d_in[1];
    const float* Wg    = (const float*)d_in[2];
    const float* bg    = (const float*)d_in[3];
    const float* Wt    = (const float*)d_in[4];
    const float* bt    = (const float*)d_in[5];
    const float* gamma = (const float*)d_in[6];
    const float* beta  = (const float*)d_in[7];
    float* out = (float*)d_out;

    char* w = (char*)d_ws;
    u16*   xa2   = (u16*)(w);                    // 78,643,200 B
    u16*   y2T   = (u16*)(w + 78643200);         // 26,214,400 B
    u16*   zb    = (u16*)(w + 104857600);        // 26,214,400 B
    u16*   Bpg   = (u16*)(w + 131072000);        //    393,216 B (packed GCN W)
    u16*   Bpt   = (u16*)(w + 131465216);        //  1,179,648 B (packed TCN W)
    float* bias2 = (float*)(w + 132644864);      //     25,600 B
    float* psum  = (float*)(w + 132670464);      //    409,600 B
    float* psq   = (float*)(w + 133080064);      //    409,600 B
    float* scale = (float*)(w + 133489664);      //      1,024 B
    float* shift = (float*)(w + 133490688);      //      1,024 B
    float* zpad  = (float*)(w + 133491712);      //      1,024 B (zeroed)

    prep_kernel<<<256, 256, 0, stream>>>(Wg, Wt, A, bg, Bpg, Bpt, bias2, zpad);
    xa_kernel<<<dim3(64, 32), 256, 0, stream>>>(x, A, xa2);
    gemm_kernel<768, false><<<NBLK, 512, 0, stream>>>(xa2, Bpg, bias2, y2T,
                                                      nullptr, nullptr, (const u16*)zpad);
    gemm_kernel<2304, true><<<NBLK, 512, 0, stream>>>(y2T, Bpt, bt, zb,
                                                      psum, psq, (const u16*)zpad);
    bn_stats_kernel<<<256, 256, 0, stream>>>(psum, psq, gamma, beta, scale, shift);
    bn_apply_kernel<<<dim3(25, 32), 256, 0, stream>>>(zb, x, scale, shift, out);
}

// Round 12
// 172.698 us; speedup vs baseline: 1.2800x; 1.2800x over previous
//
#include <hip/hip_runtime.h>
#include <math.h>

typedef unsigned short u16;
typedef short v8s __attribute__((ext_vector_type(8)));
typedef float v4f __attribute__((ext_vector_type(4)));

#define AS1 __attribute__((address_space(1)))
#define AS3 __attribute__((address_space(3)))

__device__ __forceinline__ float bf2f(u16 u) {
    union { unsigned int i; float f; } c; c.i = ((unsigned int)u) << 16; return c.f;
}
__device__ __forceinline__ u16 f2bf(float f) {
    union { float f; unsigned int i; } c; c.f = f;
    unsigned int u = c.i;
    return (u16)((u + 0x7FFFu + ((u >> 16) & 1u)) >> 16);
}
// async global->LDS, 16B per lane. LDS dest = base + lane*16 (wave-uniform base).
__device__ __forceinline__ void gload_lds16(const void* g, void* l) {
    __builtin_amdgcn_global_load_lds((const AS1 void*)(uintptr_t)g,
                                     (AS3 void*)(unsigned int)(uintptr_t)l,
                                     16, 0, 0);
}

#define Nn 32
#define Tt 64
#define Vv 25
#define NP 51200        // N*T*V positions
#define NBLK 400        // M-tiles (51200/128); psum layout [256 d][400 m]

// ---------------------------------------------------------------------------
// prep: Wgb row-major [d][768] for GEMM1 (B-in-LDS), Bpt frag-major for TCN
// (layout [dt(9)][cc(4)][wn(4)][nf(4)][kk(2)][lane(64)][e(8)] u16 so a wave's
// B-fragment load is 64 lanes x 16B contiguous), bias2[w][d], zero pad.
// ---------------------------------------------------------------------------
__global__ __launch_bounds__(256) void prep_kernel(
    const float* __restrict__ Wg, const float* __restrict__ Wt,
    const float* __restrict__ A, const float* __restrict__ bg,
    u16* __restrict__ Wgb, u16* __restrict__ Bpt,
    float* __restrict__ bias2, float* __restrict__ zpad)
{
    const int idx = blockIdx.x * 256 + threadIdx.x;
    const int stride = gridDim.x * 256;
    // TCN frag-major pack: 589824 u16
    for (int i = idx; i < 589824; i += stride) {
        const int e = i & 7, lane = (i >> 3) & 63, sub = i >> 9;
        const int kk = sub & 1, nf = (sub >> 1) & 3, wn = (sub >> 3) & 3;
        const int cc = (sub >> 5) & 3, dt = sub >> 7;
        const int d = wn * 64 + nf * 16 + (lane & 15);
        const int c = cc * 64 + kk * 32 + (lane >> 4) * 8 + e;
        Bpt[i] = f2bf(Wt[(d * 256 + c) * 9 + dt]);
    }
    // GEMM1 row-major: Wgb[d][k3*256+c]
    for (int i = idx; i < 256 * 768; i += stride) {
        int d = i / 768, r = i - d * 768, k3 = r >> 8, c = r & 255;
        Wgb[i] = f2bf(Wg[(k3 * 256 + d) * 256 + c]);
    }
    for (int i = idx; i < 25 * 256; i += stride) {
        int w = i >> 8, d = i & 255;
        float s = 0.f;
        for (int k = 0; k < 3; ++k) {
            float cs = 0.f;
            for (int v = 0; v < 25; ++v) cs += A[(k * 25 + v) * 25 + w];
            s += bg[k * 256 + d] * cs;
        }
        bias2[i] = s;
    }
    for (int i = idx; i < 256; i += stride) zpad[i] = 0.f;
}

// ---------------------------------------------------------------------------
// xa2[p=(n,t,w)][k*256+c] = sum_v x[n,c,t,v] * A[k,v,w]   (bf16 out)
// Thread = c; x-row in registers; A reads wave-uniform (s_load).
// ---------------------------------------------------------------------------
__global__ __launch_bounds__(256) void xa_kernel(
    const float* __restrict__ x, const float* __restrict__ A,
    u16* __restrict__ xa2)
{
    const int t = blockIdx.x, n = blockIdx.y;
    const int tid = threadIdx.x;              // = c
    __shared__ float xs[256 * 25];            // 25.6 KB

    for (int i = tid; i < 6400; i += 256) {
        int c = i / 25, v = i - c * 25;
        xs[i] = x[((n * 256 + c) * 64 + t) * 25 + v];
    }
    __syncthreads();

    float xr[25];
    #pragma unroll
    for (int v = 0; v < 25; ++v) xr[v] = xs[tid * 25 + v];

    const size_t pbase = ((size_t)n * 64 + t) * 25;
    #pragma unroll 1
    for (int k = 0; k < 3; ++k) {
        float o[25];
        #pragma unroll
        for (int w = 0; w < 25; ++w) {
            float acc = 0.f;
            #pragma unroll
            for (int v = 0; v < 25; ++v)
                acc = fmaf(xr[v], A[(k * 25 + v) * 25 + w], acc);
            o[w] = acc;
        }
        u16* dst = xa2 + k * 256 + tid;
        #pragma unroll
        for (int w = 0; w < 25; ++w)
            dst[(pbase + w) * 768] = f2bf(o[w]);
    }
}

// ---------------------------------------------------------------------------
// GEMM1 (r3 proven): 128x256 tile, BK=64, 512 threads = 8 waves (2M x 4N,
// per-wave 64x64). STAGE(A+B LDS) -> sync -> ds_read+MFMA -> sync. 48KB LDS.
// ---------------------------------------------------------------------------
__global__ __launch_bounds__(512) void gemm1_kernel(
    const u16* __restrict__ Ad, const u16* __restrict__ Bw,
    const float* __restrict__ bias, u16* __restrict__ outB)
{
    __shared__ u16 smem[24576];          // 48 KB
    u16* As = smem;                      // [128 rows][64 k] (swizzled)
    u16* Bs = smem + 8192;               // [256 rows][64 k] (swizzled)

    const int tid = threadIdx.x;
    const int wid = tid >> 6, lane = tid & 63;
    const int lr = lane & 15, hk = lane >> 4;
    const int wm = wid >> 2, wn = wid & 3;
    const int rA = lane >> 3, sA = lane & 7;

    const int orig = blockIdx.x;
    const int m = (orig & 7) * 50 + (orig >> 3);   // bijective XCD swizzle

    v4f acc[4][4];
    const v4f vzero = {0.f, 0.f, 0.f, 0.f};
    #pragma unroll
    for (int mf = 0; mf < 4; ++mf)
        #pragma unroll
        for (int nf = 0; nf < 4; ++nf) acc[mf][nf] = vzero;

    for (int kt = 0; kt < 12; ++kt) {
        #pragma unroll
        for (int i = 0; i < 2; ++i) {
            const int ch = wid + i * 8;
            const int row = ch * 8 + rA;
            const int ss = sA ^ rA;
            gload_lds16(Ad + (size_t)(m * 128 + row) * 768 + kt * 64 + ss * 8,
                        (char*)As + ch * 1024);
        }
        #pragma unroll
        for (int i = 0; i < 4; ++i) {
            const int ch = wid + i * 8;
            const int d = ch * 8 + rA;
            const int ss = sA ^ rA;
            gload_lds16(Bw + (size_t)d * 768 + kt * 64 + ss * 8,
                        (char*)Bs + ch * 1024);
        }
        __syncthreads();

        v8s a[4][2], b[4][2];
        #pragma unroll
        for (int mf = 0; mf < 4; ++mf)
            #pragma unroll
            for (int kk = 0; kk < 2; ++kk) {
                const int row = wm * 64 + mf * 16 + lr;
                const int slot = kk * 4 + hk;
                a[mf][kk] = *(const v8s*)((const char*)As + row * 128 + ((slot ^ (row & 7)) << 4));
            }
        #pragma unroll
        for (int nf = 0; nf < 4; ++nf)
            #pragma unroll
            for (int kk = 0; kk < 2; ++kk) {
                const int row = wn * 64 + nf * 16 + lr;
                const int slot = kk * 4 + hk;
                b[nf][kk] = *(const v8s*)((const char*)Bs + row * 128 + ((slot ^ (row & 7)) << 4));
            }
        #pragma unroll
        for (int kk = 0; kk < 2; ++kk)
            #pragma unroll
            for (int mf = 0; mf < 4; ++mf)
                #pragma unroll
                for (int nf = 0; nf < 4; ++nf)
                    acc[mf][nf] = __builtin_amdgcn_mfma_f32_16x16x32_bf16(
                        a[mf][kk], b[nf][kk], acc[mf][nf], 0, 0, 0);
        __syncthreads();
    }

    #pragma unroll
    for (int mf = 0; mf < 4; ++mf) {
        #pragma unroll
        for (int j = 0; j < 4; ++j) {
            const int p = m * 128 + wm * 64 + mf * 16 + hk * 4 + j;
            const int w = p % 25;
            #pragma unroll
            for (int nf = 0; nf < 4; ++nf) {
                const int d = wn * 64 + nf * 16 + lr;
                outB[(size_t)p * 256 + d] = f2bf(acc[mf][nf][j] + bias[w * 256 + d]);
            }
        }
    }
}

// ---------------------------------------------------------------------------
// TCN halo kernel: z[p][d] = bt[d] + sum_{dt,c} y2T[p+(dt-4)*25][c]*Wt[d,c,dt]
// Tile 128 positions x 256 d, 512 threads = 8 waves (2M x 4N, per-wave 64x64).
// KEY: stage the 336-row y2T HALO once per 64-c chunk (42KB LDS, 4 stages
// per block instead of 36) -- the 9 dt-taps then run BARRIER-FREE on the same
// buffer (per-wave ds_read at shifted rows + frag-major B from global/L2,
// prefetched one dt ahead). Safe blocks (halo within one n) skip validity
// masks; edge blocks zero invalid A-frags per-lane (t+dt-4 in [0,64)).
// Epilogue: bf16 z + deterministic per-(d, m-tile) BN partials.
// ---------------------------------------------------------------------------
__global__ __launch_bounds__(512) void tcn_halo_kernel(
    const u16* __restrict__ y2T, const u16* __restrict__ Bpt,
    const float* __restrict__ bt, u16* __restrict__ zb,
    float* __restrict__ psum, float* __restrict__ psq,
    const u16* __restrict__ zp)
{
    __shared__ u16 smem[21504];          // 336 rows x 128B = 42KB

    const int tid = threadIdx.x;
    const int wid = tid >> 6, lane = tid & 63;
    const int lr = lane & 15, hk = lane >> 4;
    const int wm = wid >> 2, wn = wid & 3;
    const int rA = lane >> 3, sA = lane & 7;

    const int orig = blockIdx.x;
    const int m = (orig & 7) * 50 + (orig >> 3);   // bijective XCD swizzle

    u16* As = smem;

    v4f acc[4][4];
    const v4f vzero = {0.f, 0.f, 0.f, 0.f};
    #pragma unroll
    for (int mf = 0; mf < 4; ++mf)
        #pragma unroll
        for (int nf = 0; nf < 4; ++nf) acc[mf][nf] = vzero;

    // per-thread t of each owned output row (constant across dt/cc)
    int tt[4];
    #pragma unroll
    for (int mf = 0; mf < 4; ++mf)
        tt[mf] = ((m * 128 + wm * 64 + mf * 16 + lr) % 1600) / 25;

    const int r0 = (m * 128) % 1600;
    const bool safe = (r0 >= 104) && (r0 <= 1368);

#define BLOAD(bank, dtv, ccv)                                                  \
    {                                                                          \
        const u16* bw = Bpt + ((((dtv)*4 + (ccv)) * 4 + wn) << 12) + lane * 8; \
        _Pragma("unroll")                                                      \
        for (int nf = 0; nf < 4; ++nf)                                         \
            _Pragma("unroll")                                                  \
            for (int kk = 0; kk < 2; ++kk)                                     \
                bb[bank][nf][kk] = *(const v8s*)(bw + ((nf * 2 + kk) << 9));   \
    }

#define CC_BODY(MASKED)                                                        \
    _Pragma("unroll 1")                                                        \
    for (int cc = 0; cc < 4; ++cc) {                                           \
        if (cc) __syncthreads();                                               \
        for (int ch = wid; ch < 42; ch += 8) {                                 \
            const int row = ch * 8 + rA;                                       \
            const int srow = m * 128 - 104 + row;                              \
            const int ss = sA ^ rA;                                            \
            const u16* src = ((unsigned)srow < 51200u)                         \
                ? (y2T + (size_t)srow * 256 + cc * 64 + ss * 8) : zp;          \
            gload_lds16(src, (char*)As + ch * 1024);                           \
        }                                                                      \
        __syncthreads();                                                       \
        v8s bb[2][4][2];                                                       \
        BLOAD(0, 0, cc)                                                        \
        _Pragma("unroll")                                                      \
        for (int dt = 0; dt < 9; ++dt) {                                       \
            if (dt < 8) BLOAD((dt + 1) & 1, dt + 1, cc)                        \
            v8s a[4][2];                                                       \
            _Pragma("unroll")                                                  \
            for (int mf = 0; mf < 4; ++mf)                                     \
                _Pragma("unroll")                                              \
                for (int kk = 0; kk < 2; ++kk) {                               \
                    const int lrow = 104 + wm * 64 + mf * 16 + lr + (dt - 4) * 25; \
                    const int slot = kk * 4 + hk;                              \
                    a[mf][kk] = *(const v8s*)((const char*)As + lrow * 128 +   \
                                              ((slot ^ (lrow & 7)) << 4));     \
                }                                                              \
            if (MASKED) {                                                      \
                _Pragma("unroll")                                              \
                for (int mf = 0; mf < 4; ++mf) {                               \
                    const bool ok = (unsigned)(tt[mf] + dt - 4) < 64u;         \
                    a[mf][0] = ok ? a[mf][0] : (v8s)(short)0;                  \
                    a[mf][1] = ok ? a[mf][1] : (v8s)(short)0;                  \
                }                                                              \
            }                                                                  \
            _Pragma("unroll")                                                  \
            for (int kk = 0; kk < 2; ++kk)                                     \
                _Pragma("unroll")                                              \
                for (int mf = 0; mf < 4; ++mf)                                 \
                    _Pragma("unroll")                                          \
                    for (int nf = 0; nf < 4; ++nf)                             \
                        acc[mf][nf] = __builtin_amdgcn_mfma_f32_16x16x32_bf16( \
                            a[mf][kk], bb[dt & 1][nf][kk], acc[mf][nf], 0, 0, 0); \
        }                                                                      \
    }

    if (safe) { CC_BODY(false) } else { CC_BODY(true) }
#undef CC_BODY
#undef BLOAD

    // ---- epilogue: bias, bf16 z, BN partials ----
    float s[4], q[4];
    #pragma unroll
    for (int nf = 0; nf < 4; ++nf) {
        const int d = wn * 64 + nf * 16 + lr;
        const float bbv = bt[d];
        s[nf] = 0.f; q[nf] = 0.f;
        #pragma unroll
        for (int mf = 0; mf < 4; ++mf) {
            #pragma unroll
            for (int j = 0; j < 4; ++j) {
                const int p = m * 128 + wm * 64 + mf * 16 + hk * 4 + j;
                const float zz = acc[mf][nf][j] + bbv;
                zb[(size_t)p * 256 + d] = f2bf(zz);
                s[nf] += zz; q[nf] += zz * zz;
            }
        }
        s[nf] += __shfl_xor(s[nf], 16); s[nf] += __shfl_xor(s[nf], 32);
        q[nf] += __shfl_xor(q[nf], 16); q[nf] += __shfl_xor(q[nf], 32);
    }
    __syncthreads();
    float* red = (float*)smem;       // [2 wm][256 d] s, then q (4KB)
    if (hk == 0) {
        #pragma unroll
        for (int nf = 0; nf < 4; ++nf) {
            const int d = wn * 64 + nf * 16 + lr;
            red[wm * 256 + d] = s[nf];
            red[512 + wm * 256 + d] = q[nf];
        }
    }
    __syncthreads();
    if (tid < 256) {
        psum[(size_t)tid * NBLK + m] = red[tid] + red[256 + tid];
        psq[(size_t)tid * NBLK + m]  = red[512 + tid] + red[768 + tid];
    }
}

// ---------------------------------------------------------------------------
// BN stats: reduce 400 m-tile partials per channel -> scale/shift
// ---------------------------------------------------------------------------
__global__ __launch_bounds__(256) void bn_stats_kernel(
    const float* __restrict__ psum, const float* __restrict__ psq,
    const float* __restrict__ gamma, const float* __restrict__ beta,
    float* __restrict__ scale, float* __restrict__ shift)
{
    const int d = blockIdx.x, tid = threadIdx.x;
    float s = 0.f, q = 0.f;
    for (int i = tid; i < NBLK; i += 256) {
        s += psum[(size_t)d * NBLK + i];
        q += psq[(size_t)d * NBLK + i];
    }
    #pragma unroll
    for (int off = 32; off; off >>= 1) {
        s += __shfl_down(s, off);
        q += __shfl_down(q, off);
    }
    __shared__ float rs[4], rq[4];
    if ((tid & 63) == 0) { rs[tid >> 6] = s; rq[tid >> 6] = q; }
    __syncthreads();
    if (tid == 0) {
        s = rs[0] + rs[1] + rs[2] + rs[3];
        q = rq[0] + rq[1] + rq[2] + rq[3];
        const float mean = s / 51200.f;
        const float var = q / 51200.f - mean * mean;
        const float inv = rsqrtf(var + 1e-5f);
        scale[d] = gamma[d] * inv;
        shift[d] = beta[d] - gamma[d] * inv * mean;
    }
}

// ---------------------------------------------------------------------------
// out[n,d,tv] = relu(z[p][d]*scale[d]+shift[d] + x[n,d,tv]); LDS transpose.
// ---------------------------------------------------------------------------
__global__ __launch_bounds__(256) void bn_apply_kernel(
    const u16* __restrict__ zb, const float* __restrict__ x,
    const float* __restrict__ scale, const float* __restrict__ shift,
    float* __restrict__ out)
{
    const int chunk = blockIdx.x;   // 0..24
    const int n = blockIdx.y;       // 0..31
    const int tid = threadIdx.x;
    __shared__ u16 zs[128 * 66];    // 16.9 KB, padded rows
    const size_t p0 = (size_t)n * 1600 + chunk * 64;

    for (int half = 0; half < 2; ++half) {
        const int d0 = half * 128;
        if (half) __syncthreads();
        for (int i = tid; i < 128 * 64; i += 256) {
            const int pl = i >> 7, dl = i & 127;
            zs[dl * 66 + pl] = zb[(p0 + pl) * 256 + d0 + dl];
        }
        __syncthreads();
        for (int i = tid; i < 128 * 64; i += 256) {
            const int dl = i >> 6, j = i & 63;
            const int d = d0 + dl;
            const size_t addr = ((size_t)n * 256 + d) * 1600 + chunk * 64 + j;
            const float r = bf2f(zs[dl * 66 + j]) * scale[d] + shift[d] + x[addr];
            out[addr] = fmaxf(r, 0.f);
        }
    }
}

extern "C" void kernel_launch(void* const* d_in, const int* in_sizes, int n_in,
                              void* d_out, int out_size, void* d_ws, size_t ws_size,
                              hipStream_t stream)
{
    const float* x     = (const float*)d_in[0];
    const float* A     = (const float*)d_in[1];
    const float* Wg    = (const float*)d_in[2];
    const float* bg    = (const float*)d_in[3];
    const float* Wt    = (const float*)d_in[4];
    const float* bt    = (const float*)d_in[5];
    const float* gamma = (const float*)d_in[6];
    const float* beta  = (const float*)d_in[7];
    float* out = (float*)d_out;

    char* w = (char*)d_ws;
    u16*   xa2   = (u16*)(w);                    // 78,643,200 B
    u16*   y2T   = (u16*)(w + 78643200);         // 26,214,400 B
    u16*   zb    = (u16*)(w + 104857600);        // 26,214,400 B
    u16*   Wgb   = (u16*)(w + 131072000);        //    393,216 B (row-major GCN W)
    u16*   Bpt   = (u16*)(w + 131465216);        //  1,179,648 B (frag-major TCN W)
    float* bias2 = (float*)(w + 132644864);      //     25,600 B
    float* psum  = (float*)(w + 132670464);      //    409,600 B
    float* psq   = (float*)(w + 133080064);      //    409,600 B
    float* scale = (float*)(w + 133489664);      //      1,024 B
    float* shift = (float*)(w + 133490688);      //      1,024 B
    float* zpad  = (float*)(w + 133491712);      //      1,024 B (zeroed)

    prep_kernel<<<256, 256, 0, stream>>>(Wg, Wt, A, bg, Wgb, Bpt, bias2, zpad);
    xa_kernel<<<dim3(64, 32), 256, 0, stream>>>(x, A, xa2);
    gemm1_kernel<<<NBLK, 512, 0, stream>>>(xa2, Wgb, bias2, y2T);
    tcn_halo_kernel<<<NBLK, 512, 0, stream>>>(y2T, Bpt, bt, zb, psum, psq,
                                              (const u16*)zpad);
    bn_stats_kernel<<<256, 256, 0, stream>>>(psum, psq, gamma, beta, scale, shift);
    bn_apply_kernel<<<dim3(25, 32), 256, 0, stream>>>(zb, x, scale, shift, out);
}